// Round 5
// baseline (59.897 us; speedup 1.0000x reference)
//
#include <hip/hip_runtime.h>
#include <math.h>
#include <float.h>

#define BATCH 128
#define LEN   100000
#define BPR   8                  // blocks per row
#define BCHUNK (LEN / BPR)       // 12500 elements per block
#define BVEC  (BCHUNK / 4)       // 3125 float4 vectors per block
#define T     512                // threads per block (8 waves)
#define NG    7                  // groups: 6 full (512 vec) + tail (53 vec)
#define TAILV (BVEC - (NG - 1) * T)   // 53 vectors in last group
#define NST   7                  // stripes per block == NG
#define STRE  (T * 4)            // 2048 elems per full stripe
#define TAILE (TAILV * 4)        // 212 elems in last stripe
#define NSEG  (BATCH * BPR)      // 1024 block-level table entries
#define NSTR  (NSEG * NST)       // 7168 stripe-level entries

// ---------- workspace layout ----------
struct WS {
    int*   lt_tab; int* ht_tab; int* lp_tab; int* hp_tab;   // [NSEG]
    float* bce_blk; float* sm_blk;                          // [NSEG]
    float* cmin; float* cmax;                               // [NSTR]
    float* wmn; float* wmx;                                 // [2*BATCH]
};

static inline WS ws_layout(void* d_ws) {
    WS w;
    w.lt_tab  = (int*)d_ws;
    w.ht_tab  = w.lt_tab + NSEG;
    w.lp_tab  = w.ht_tab + NSEG;
    w.hp_tab  = w.lp_tab + NSEG;
    w.bce_blk = (float*)(w.hp_tab + NSEG);
    w.sm_blk  = w.bce_blk + NSEG;
    w.cmin    = w.sm_blk  + NSEG;
    w.cmax    = w.cmin    + NSTR;
    w.wmn     = w.cmax    + NSTR;
    w.wmx     = w.wmn     + 2 * BATCH;
    return w;
}

// ---------- main fused pass ----------
// Round 4 showed TLP (occupancy) is the live variable. This round: grid =
// 128x8 = 1024 blocks = EXACTLY 4 resident blocks/CU (32 waves) in a single
// generation (launch_bounds(512,8) caps VGPR at 64). 2x work per thread
// amortizes per-block overhead. Signal min/max recorded per STRIPE (one
// group's 2048-elem span) so k_rows' boundary scan shrinks to <=2x2048.

__global__ __launch_bounds__(T, 8) void k_main(
        const float* __restrict__ sig,
        const float* __restrict__ pred,
        const float* __restrict__ targ,
        int* __restrict__ lt_tab, int* __restrict__ ht_tab,
        int* __restrict__ lp_tab, int* __restrict__ hp_tab,
        float* __restrict__ bce_blk, float* __restrict__ sm_blk,
        float* __restrict__ cmin_tab, float* __restrict__ cmax_tab) {
    const int b   = blockIdx.y;
    const int blk = blockIdx.x;          // 0..BPR-1
    const int tid = threadIdx.x;
    const size_t row = (size_t)b * LEN;
    const float* prow = pred + row;
    const float* trow = targ + row;
    const float* srow = sig  + row;
    const int base = blk * BCHUNK;
    const int w = tid >> 6, lane = tid & 63;

    __shared__ float s_stmn[8][NST], s_stmx[8][NST];
    __shared__ float s_bce[8], s_sm[8];
    __shared__ int   s_lt[8], s_ht[8], s_lp[8], s_hp[8];

    float bce = 0.0f, sm = 0.0f;
    unsigned tmask = 0u, pmask = 0u;

    #pragma unroll
    for (int k = 0; k < NG; ++k) {
        const bool act = (k < NG - 1) || (tid < TAILV);
        float gmn = FLT_MAX, gmx = -FLT_MAX;     // per-group (stripe) min/max
        if (act) {
            const int l0 = base + (tid + k * T) * 4;
            const float4 p4 = *reinterpret_cast<const float4*>(prow + l0);
            const float4 t4 = *reinterpret_cast<const float4*>(trow + l0);
            const float4 s4 = *reinterpret_cast<const float4*>(srow + l0);
            float sg0, sg1, sg2, sg3;
            #define ONE_ELEM(pp, tt, ss, sgv, BIT) { \
                const float ap = fabsf(pp); \
                const float ee = __expf(-ap); \
                const float zz = 1.0f + ee; \
                const float rr = __builtin_amdgcn_rcpf(zz); \
                bce += fmaxf(pp, 0.0f) - (pp) * (tt) + __logf(zz); \
                sgv = ((pp) >= 0.0f) ? rr : ee * rr; \
                tmask |= ((tt) > 0.5f) ? (1u << (BIT)) : 0u; \
                pmask |= ((pp) > 0.0f) ? (1u << (BIT)) : 0u; \
                gmn = fminf(gmn, (ss)); gmx = fmaxf(gmx, (ss)); }
            ONE_ELEM(p4.x, t4.x, s4.x, sg0, 4 * k + 0)
            ONE_ELEM(p4.y, t4.y, s4.y, sg1, 4 * k + 1)
            ONE_ELEM(p4.z, t4.z, s4.z, sg2, 4 * k + 2)
            ONE_ELEM(p4.w, t4.w, s4.w, sg3, 4 * k + 3)
            #undef ONE_ELEM
            sm += fabsf(sg1 - sg0) + fabsf(sg2 - sg1) + fabsf(sg3 - sg2);
            const float prev3 = __shfl_up(sg3, 1);   // lane-1's sg3
            if (lane == 0) {
                if (l0 > 0) {                        // wave boundary: recompute
                    const float pp = prow[l0 - 1];
                    const float ee = __expf(-fabsf(pp));
                    const float rr = __builtin_amdgcn_rcpf(1.0f + ee);
                    const float sp = (pp >= 0.0f) ? rr : ee * rr;
                    sm += fabsf(sg0 - sp);
                }
            } else {
                sm += fabsf(sg0 - prev3);
            }
        }
        // full-wave reduce of the stripe min/max (inactive lanes hold identity)
        #pragma unroll
        for (int o = 32; o > 0; o >>= 1) {
            gmn = fminf(gmn, __shfl_xor(gmn, o));
            gmx = fmaxf(gmx, __shfl_xor(gmx, o));
        }
        if (lane == 0) { s_stmn[w][k] = gmn; s_stmx[w][k] = gmx; }
    }

    // ---- decode index masks (bit position monotone in element index) ----
    int lt = LEN, ht = -1, lp = LEN, hp = -1;
    if (tmask) {
        const int f = __ffs(tmask) - 1;
        const int h = 31 - __clz((int)tmask);
        lt = base + (tid + (f >> 2) * T) * 4 + (f & 3);
        ht = base + (tid + (h >> 2) * T) * 4 + (h & 3);
    }
    if (pmask) {
        const int f = __ffs(pmask) - 1;
        const int h = 31 - __clz((int)pmask);
        lp = base + (tid + (f >> 2) * T) * 4 + (f & 3);
        hp = base + (tid + (h >> 2) * T) * 4 + (h & 3);
    }

    // ---- block-wide wave reductions ----
    #pragma unroll
    for (int o = 32; o > 0; o >>= 1) {
        bce += __shfl_xor(bce, o);
        sm  += __shfl_xor(sm,  o);
        lt   = min(lt, __shfl_xor(lt, o));
        ht   = max(ht, __shfl_xor(ht, o));
        lp   = min(lp, __shfl_xor(lp, o));
        hp   = max(hp, __shfl_xor(hp, o));
    }
    if (lane == 0) {
        s_bce[w] = bce; s_sm[w] = sm;
        s_lt[w] = lt; s_ht[w] = ht; s_lp[w] = lp; s_hp[w] = hp;
    }
    __syncthreads();

    const int e = b * BPR + blk;
    if (tid == 0) {
        float B = 0.0f, S = 0.0f;
        int LT = LEN, HT = -1, LP = LEN, HP = -1;
        #pragma unroll
        for (int i = 0; i < 8; ++i) {
            B += s_bce[i]; S += s_sm[i];
            LT = min(LT, s_lt[i]); HT = max(HT, s_ht[i]);
            LP = min(LP, s_lp[i]); HP = max(HP, s_hp[i]);
        }
        bce_blk[e] = B; sm_blk[e] = S;
        lt_tab[e] = LT; ht_tab[e] = HT;
        lp_tab[e] = LP; hp_tab[e] = HP;
    }
    if (tid < NST) {
        float mn = s_stmn[0][tid], mx = s_stmx[0][tid];
        #pragma unroll
        for (int i = 1; i < 8; ++i) {
            mn = fminf(mn, s_stmn[i][tid]); mx = fmaxf(mx, s_stmx[i][tid]);
        }
        cmin_tab[e * NST + tid] = mn;
        cmax_tab[e * NST + tid] = mx;
    }
}

// ---------- windowed min/max per (row, which) ----------

__device__ __forceinline__ int stripe_id(int l) {
    const int bk = l / BCHUNK;
    const int rem = l - bk * BCHUNK;
    int st = rem / STRE;                 // 12499/2048 = 6 max
    return bk * NST + st;
}
__device__ __forceinline__ int stripe_start(int sid) {
    const int bk = sid / NST, st = sid - bk * NST;
    return bk * BCHUNK + st * STRE;
}
__device__ __forceinline__ int stripe_end(int sid) {     // inclusive
    const int bk = sid / NST, st = sid - bk * NST;
    return bk * BCHUNK + st * STRE + ((st < NST - 1) ? STRE : TAILE) - 1;
}

__global__ __launch_bounds__(T) void k_rows(
        const float* __restrict__ sig,
        const int* __restrict__ lt_tab, const int* __restrict__ ht_tab,
        const int* __restrict__ lp_tab, const int* __restrict__ hp_tab,
        const float* __restrict__ cmin_tab, const float* __restrict__ cmax_tab,
        float* __restrict__ wmn, float* __restrict__ wmx) {
    const int b     = blockIdx.x;
    const int which = blockIdx.y;          // 0 = target window, 1 = pred window
    const int tid   = threadIdx.x;
    const int* lo_tab = which ? lp_tab : lt_tab;
    const int* hi_tab = which ? hp_tab : ht_tab;

    // derive row lo/hi from the BPR per-block entries (wave 0 computes)
    int lo = LEN, hi = -1;
    if (tid < BPR) { lo = lo_tab[b * BPR + tid]; hi = hi_tab[b * BPR + tid]; }
    #pragma unroll
    for (int o = 32; o > 0; o >>= 1) {
        lo = min(lo, __shfl_xor(lo, o));
        hi = max(hi, __shfl_xor(hi, o));
    }
    __shared__ int s_lo, s_hi;
    if (tid == 0) { s_lo = lo; s_hi = hi; }
    __syncthreads();
    lo = s_lo; hi = s_hi;

    float mn = FLT_MAX, mx = -FLT_MAX;
    if (lo < LEN) {
        const float* srow = sig + (size_t)b * LEN;
        const int sl = stripe_id(lo), sh = stripe_id(hi);
        const int e1 = (sl == sh) ? hi : stripe_end(sl);
        for (int l = lo + tid; l <= e1; l += T) {
            const float x = srow[l]; mn = fminf(mn, x); mx = fmaxf(mx, x);
        }
        if (sh > sl) {
            for (int l = stripe_start(sh) + tid; l <= hi; l += T) {
                const float x = srow[l]; mn = fminf(mn, x); mx = fmaxf(mx, x);
            }
            const float* cmin_row = cmin_tab + b * BPR * NST;
            const float* cmax_row = cmax_tab + b * BPR * NST;
            for (int s = sl + 1 + tid; s < sh; s += T) {
                mn = fminf(mn, cmin_row[s]); mx = fmaxf(mx, cmax_row[s]);
            }
        }
    }
    #pragma unroll
    for (int o = 32; o > 0; o >>= 1) {
        mn = fminf(mn, __shfl_xor(mn, o));
        mx = fmaxf(mx, __shfl_xor(mx, o));
    }
    __shared__ float sh_mn[8], sh_mx[8];
    const int w = tid >> 6, lane = tid & 63;
    if (lane == 0) { sh_mn[w] = mn; sh_mx[w] = mx; }
    __syncthreads();
    if (tid == 0) {
        float MN = FLT_MAX, MX = -FLT_MAX;
        #pragma unroll
        for (int i = 0; i < 8; ++i) {
            MN = fminf(MN, sh_mn[i]); MX = fmaxf(MX, sh_mx[i]);
        }
        if (lo >= LEN) { MN = 1e30f; MX = -1e30f; }   // invalid marker: MX < MN
        wmn[which * BATCH + b] = MN;
        wmx[which * BATCH + b] = MX;
    }
}

// ---------- final combine ----------

__global__ void k_combine(const float* __restrict__ bce_blk,
                          const float* __restrict__ sm_blk,
                          const float* __restrict__ wmn,
                          const float* __restrict__ wmx,
                          float* __restrict__ out) {
    const int tid = threadIdx.x;
    float acc_b = 0.0f, acc_s = 0.0f, acc_a = 0.0f;
    for (int i = tid; i < NSEG; i += 256) { acc_b += bce_blk[i]; acc_s += sm_blk[i]; }
    if (tid < BATCH) {
        const float tmn = wmn[tid],          tmx = wmx[tid];
        const float pmn = wmn[BATCH + tid],  pmx = wmx[BATCH + tid];
        if (tmx >= tmn && pmx >= pmn) {      // both windows valid
            const float ta = tmx - tmn;
            const float pa = pmx - pmn;
            const float d  = fabsf(ta - pa);
            acc_a = (ta > 1e-6f) ? d / (ta + 1e-6f) : d;
        }
    }
    #pragma unroll
    for (int o = 32; o > 0; o >>= 1) {
        acc_b += __shfl_xor(acc_b, o);
        acc_s += __shfl_xor(acc_s, o);
        acc_a += __shfl_xor(acc_a, o);
    }
    __shared__ float sb[4], ss[4], sa[4];
    const int w = tid >> 6, lane = tid & 63;
    if (lane == 0) { sb[w] = acc_b; ss[w] = acc_s; sa[w] = acc_a; }
    __syncthreads();
    if (tid == 0) {
        const double B = (double)(sb[0] + sb[1] + sb[2] + sb[3]);
        const double S = (double)(ss[0] + ss[1] + ss[2] + ss[3]);
        const double A = (double)(sa[0] + sa[1] + sa[2] + sa[3]);
        const double bce = B / ((double)BATCH * (double)LEN);
        const double smo = S / ((double)BATCH * (double)(LEN - 1));
        const double amp = A / (double)BATCH;
        out[0] = (float)(1.0 * bce + 0.5 * amp + 0.3 * smo);
    }
}

// ---------- launch ----------

extern "C" void kernel_launch(void* const* d_in, const int* in_sizes, int n_in,
                              void* d_out, int out_size, void* d_ws, size_t ws_size,
                              hipStream_t stream) {
    const float* signals = (const float*)d_in[0];   // (B, 1, L)
    const float* preds   = (const float*)d_in[1];   // (B, L, 1)
    const float* targs   = (const float*)d_in[2];   // (B, L, 1)
    float* out = (float*)d_out;
    WS w = ws_layout(d_ws);

    dim3 gm(BPR, BATCH);                 // 1024 blocks = 4/CU, one generation
    k_main<<<gm, T, 0, stream>>>(signals, preds, targs,
                                 w.lt_tab, w.ht_tab, w.lp_tab, w.hp_tab,
                                 w.bce_blk, w.sm_blk, w.cmin, w.cmax);

    dim3 gr(BATCH, 2);
    k_rows<<<gr, T, 0, stream>>>(signals,
                                 w.lt_tab, w.ht_tab, w.lp_tab, w.hp_tab,
                                 w.cmin, w.cmax, w.wmn, w.wmx);

    k_combine<<<1, 256, 0, stream>>>(w.bce_blk, w.sm_blk, w.wmn, w.wmx, out);
}